// Round 1
// baseline (481.143 us; speedup 1.0000x reference)
//
#include <hip/hip_runtime.h>
#include <hip/hip_bf16.h>
#include <stdint.h>

// Problem shape (fixed by setup_inputs): x[8,2048,1024] fp32, W[4096,1024],
// b[4096], gA/lA[8,1024], gB/lB[4096,8]. out[8,2048,4096] fp32.
// M = 16384, K = 1024, N = 4096, R = 8, SCALE = 16/8 = 2.0.
//
// Strategy: W_eff = W + 2*(gB@gA + lB@lA)  (tiny), then out = x @ W_eff^T + b
// as a single bf16-MFMA GEMM (m97 ladder structure: 128x128 tile, BK=32,
// global_load_lds width=16, 16x16x32 bf16 MFMA, 4x4 acc per wave).
// Workspace: [0, 33.5MB) = x in bf16; [33.5MB, 42MB) = W_eff in bf16.

#define M_DIM 16384
#define N_DIM 4096
#define K_DIM 1024
#define R_DIM 8
#define LORA_SCALE 2.0f

typedef __attribute__((ext_vector_type(4))) float  f32x4;
typedef __attribute__((ext_vector_type(8))) __bf16 bf16x8;
typedef __attribute__((ext_vector_type(4))) unsigned short u16x4;
typedef __attribute__((ext_vector_type(8))) unsigned short u16x8;

__device__ __forceinline__ unsigned short f2bf(float f) {
  union { float f; uint32_t u; } v; v.f = f;
  uint32_t u = v.u;
  return (unsigned short)((u + 0x7fffu + ((u >> 16) & 1u)) >> 16);
}

// ---------------- prep 1: x fp32 -> bf16 ----------------
__global__ void cvt_x_kernel(const float* __restrict__ x,
                             unsigned short* __restrict__ xb) {
  long i = ((long)blockIdx.x * blockDim.x + threadIdx.x) * 8;
  f32x4 a = *(const f32x4*)(x + i);
  f32x4 b = *(const f32x4*)(x + i + 4);
  u16x8 o;
  o[0] = f2bf(a[0]); o[1] = f2bf(a[1]); o[2] = f2bf(a[2]); o[3] = f2bf(a[3]);
  o[4] = f2bf(b[0]); o[5] = f2bf(b[1]); o[6] = f2bf(b[2]); o[7] = f2bf(b[3]);
  *(u16x8*)(xb + i) = o;
}

// ---------------- prep 2: W_eff = W + 2*(gB@gA + lB@lA) -> bf16 ----------------
__global__ void weff_kernel(const float* __restrict__ W,
                            const float* __restrict__ gA,
                            const float* __restrict__ gB,
                            const float* __restrict__ lA,
                            const float* __restrict__ lB,
                            unsigned short* __restrict__ Wb) {
  int idx = blockIdx.x * blockDim.x + threadIdx.x;   // over N*K/4
  int o  = idx >> 8;            // K/4 = 256
  int i4 = (idx & 255) << 2;
  f32x4 w = *(const f32x4*)(W + ((long)o << 10) + i4);
#pragma unroll
  for (int r = 0; r < R_DIM; ++r) {
    float cg = LORA_SCALE * gB[o * R_DIM + r];
    float cl = LORA_SCALE * lB[o * R_DIM + r];
    f32x4 ga = *(const f32x4*)(gA + (r << 10) + i4);
    f32x4 la = *(const f32x4*)(lA + (r << 10) + i4);
    w += cg * ga + cl * la;
  }
  u16x4 out;
  out[0] = f2bf(w[0]); out[1] = f2bf(w[1]); out[2] = f2bf(w[2]); out[3] = f2bf(w[3]);
  *(u16x4*)(Wb + (long)idx * 4) = out;
}

// ---------------- GEMM: C[M][N] = Xb[M][K] @ Wb[N][K]^T + bias ----------------
#define BM 128
#define BN 128
#define BK 32

#define GLOAD_LDS16(g, l)                                              \
  __builtin_amdgcn_global_load_lds(                                    \
      (const __attribute__((address_space(1))) void*)(g),              \
      (__attribute__((address_space(3))) void*)(l), 16, 0, 0)

__global__ __launch_bounds__(256)
void gemm_bias_kernel(const unsigned short* __restrict__ A,   // [M][K] bf16
                      const unsigned short* __restrict__ B,   // [N][K] bf16
                      const float* __restrict__ bias,         // [N]
                      float* __restrict__ C) {                // [M][N]
  __shared__ unsigned short As[BM * BK];   // row-major [row][k], stride 32
  __shared__ unsigned short Bs[BN * BK];

  const int tid  = threadIdx.x;
  const int wave = tid >> 6;
  const int lane = tid & 63;
  const int wm = (wave >> 1) * 64;     // wave row origin in tile
  const int wn = (wave & 1) * 64;      // wave col origin in tile
  const int lr = lane & 15;            // m (A) / n (B) within 16-tile
  const int lq = lane >> 4;            // k-quad

  const int m0 = blockIdx.y * BM;
  const int n0 = blockIdx.x * BN;

  f32x4 acc[4][4] = {};

  // staging: chunk c = iter*256 + tid covers LDS row c>>2, elems (c&3)*8..+7
  const int srow = tid >> 2;
  const int skc  = (tid & 3) * 8;
  const unsigned short* Ag0 = A + (long)(m0 + srow) * K_DIM + skc;
  const unsigned short* Ag1 = A + (long)(m0 + srow + 64) * K_DIM + skc;
  const unsigned short* Bg0 = B + (long)(n0 + srow) * K_DIM + skc;
  const unsigned short* Bg1 = B + (long)(n0 + srow + 64) * K_DIM + skc;
  unsigned short* AsP0 = As + tid * 8;           // byte offset tid*16
  unsigned short* AsP1 = As + (256 + tid) * 8;
  unsigned short* BsP0 = Bs + tid * 8;
  unsigned short* BsP1 = Bs + (256 + tid) * 8;

  for (int k0 = 0; k0 < K_DIM; k0 += BK) {
    GLOAD_LDS16(Ag0 + k0, AsP0);
    GLOAD_LDS16(Ag1 + k0, AsP1);
    GLOAD_LDS16(Bg0 + k0, BsP0);
    GLOAD_LDS16(Bg1 + k0, BsP1);
    __syncthreads();   // drains vmcnt: DMA into LDS complete

    bf16x8 af[4], bf[4];
#pragma unroll
    for (int i = 0; i < 4; ++i)
      af[i] = *(const bf16x8*)(As + (wm + i * 16 + lr) * BK + lq * 8);
#pragma unroll
    for (int j = 0; j < 4; ++j)
      bf[j] = *(const bf16x8*)(Bs + (wn + j * 16 + lr) * BK + lq * 8);

#pragma unroll
    for (int i = 0; i < 4; ++i)
#pragma unroll
      for (int j = 0; j < 4; ++j)
        acc[i][j] = __builtin_amdgcn_mfma_f32_16x16x32_bf16(
            af[i], bf[j], acc[i][j], 0, 0, 0);

    __syncthreads();   // frags consumed before next DMA overwrites LDS
  }

  // epilogue: C[m_tile + lq*4+rg][n_tile + lr] = acc + bias
  const int cm = m0 + wm;
  const int cn = n0 + wn;
#pragma unroll
  for (int j = 0; j < 4; ++j) {
    const int col = cn + j * 16 + lr;
    const float bv = bias[col];
#pragma unroll
    for (int i = 0; i < 4; ++i) {
      const int rowb = cm + i * 16 + lq * 4;
#pragma unroll
      for (int rg = 0; rg < 4; ++rg)
        C[(long)(rowb + rg) * N_DIM + col] = acc[i][j][rg] + bv;
    }
  }
}

extern "C" void kernel_launch(void* const* d_in, const int* in_sizes, int n_in,
                              void* d_out, int out_size, void* d_ws, size_t ws_size,
                              hipStream_t stream) {
  const float* x  = (const float*)d_in[0];
  const float* W  = (const float*)d_in[1];
  const float* b  = (const float*)d_in[2];
  const float* gA = (const float*)d_in[3];
  const float* gB = (const float*)d_in[4];
  const float* lA = (const float*)d_in[5];
  const float* lB = (const float*)d_in[6];
  float* out = (float*)d_out;

  unsigned short* xb = (unsigned short*)d_ws;                       // 33.5 MB
  unsigned short* Wb = xb + (long)M_DIM * K_DIM;                    // 8.4 MB

  // x -> bf16: 16777216 elems / 8 per thread = 2097152 threads
  cvt_x_kernel<<<8192, 256, 0, stream>>>(x, xb);
  // W_eff: 4096*1024/4 = 1048576 threads
  weff_kernel<<<4096, 256, 0, stream>>>(W, gA, gB, lA, lB, Wb);
  // GEMM: grid 32 x 128
  dim3 grid(N_DIM / BN, M_DIM / BM);
  gemm_bias_kernel<<<grid, 256, 0, stream>>>(xb, Wb, b, out);
}